// Round 1
// baseline (568.537 us; speedup 1.0000x reference)
//
#include <hip/hip_runtime.h>
#include <hip/hip_bf16.h>

// Problem constants (AlignmentMatrix): B=128, L1=1024, L2=128, H2=600
static constexpr int Bn  = 128;
static constexpr int L1c = 1024;
static constexpr int L2c = 128;
static constexpr int H2c = 600;

#define BM 128
#define BN 128
#define BK 64
#define LDK 72              // BK + 8 pad shorts; row stride 144 B (16B-aligned, non-pow2 banks)
static constexpr int NCHUNK = (H2c + BK - 1) / BK;   // 10 (last chunk 24 valid, zero-padded)

typedef __attribute__((ext_vector_type(8))) __bf16 bf16x8;
typedef __attribute__((ext_vector_type(4))) float  f32x4;

__device__ __forceinline__ unsigned short f2bf(float f) {
    // round-to-nearest-even f32 -> bf16
    unsigned int u = __float_as_uint(f);
    u += 0x7FFFu + ((u >> 16) & 1u);
    return (unsigned short)(u >> 16);
}

__global__ __launch_bounds__(256)
void align_kernel(const float* __restrict__ ctx, const float* __restrict__ asp,
                  const float* __restrict__ w_u, float* __restrict__ out)
{
    __shared__ unsigned short As[BM * LDK];   // 18432 B, (ctx*w3) in bf16
    __shared__ unsigned short Bs[BN * LDK];   // 18432 B, asp in bf16
    __shared__ float sA[BM];                  // s_ctx for block rows
    __shared__ float sB[BN];                  // s_asp for block cols

    const int b       = blockIdx.y;
    const int rowBase = blockIdx.x * BM;
    const int tid  = threadIdx.x;
    const int lane = tid & 63;
    const int wave = tid >> 6;     // 4 waves: 2x2 grid of 64x64 sub-tiles
    const int wm   = wave >> 1;
    const int wn   = wave & 1;
    const int quad = lane >> 4;
    const int l15  = lane & 15;

    const float* ctx_base = ctx + ((size_t)b * L1c + rowBase) * H2c;
    const float* asp_base = asp + (size_t)b * L2c * H2c;
    const float* w1 = w_u;
    const float* w2 = w_u + H2c;
    const float* w3 = w_u + 2 * H2c;

    // staging assignment: thread (srow,scg) loads rows {srow+16i}, cols [scg*4, scg*4+3]
    const int srow = tid >> 4;     // 0..15
    const int scg  = tid & 15;     // 0..15
    const int d0   = scg * 4;      // 0..60

    f32x4 acc[4][4];
    const f32x4 zero4 = {0.f, 0.f, 0.f, 0.f};
#pragma unroll
    for (int i = 0; i < 4; i++)
#pragma unroll
        for (int j = 0; j < 4; j++) acc[i][j] = zero4;

    float sctxp[8], saspp[8];
#pragma unroll
    for (int i = 0; i < 8; i++) { sctxp[i] = 0.f; saspp[i] = 0.f; }

    for (int kc = 0; kc < NCHUNK; kc++) {
        const int kd = kc * BK + d0;
        const bool valid = (kd < H2c);   // kd%4==0 and H2c%4==0 -> whole float4 valid

        float4 w1v = valid ? *(const float4*)(w1 + kd) : make_float4(0.f,0.f,0.f,0.f);
        float4 w2v = valid ? *(const float4*)(w2 + kd) : make_float4(0.f,0.f,0.f,0.f);
        float4 w3v = valid ? *(const float4*)(w3 + kd) : make_float4(0.f,0.f,0.f,0.f);

        // ---- stage A tile = (ctx * w3) in bf16; fuse s_ctx partial = ctx . w1 ----
#pragma unroll
        for (int i = 0; i < 8; i++) {
            const int row = srow + i * 16;
            float4 av = valid ? *(const float4*)(ctx_base + row * H2c + kd)
                              : make_float4(0.f,0.f,0.f,0.f);
            sctxp[i] += av.x * w1v.x + av.y * w1v.y + av.z * w1v.z + av.w * w1v.w;
            ushort4 pv;
            pv.x = f2bf(av.x * w3v.x);
            pv.y = f2bf(av.y * w3v.y);
            pv.z = f2bf(av.z * w3v.z);
            pv.w = f2bf(av.w * w3v.w);
            *(ushort4*)(&As[row * LDK + d0]) = pv;
        }
        // ---- stage B tile = asp in bf16; fuse s_asp partial = asp . w2 ----
#pragma unroll
        for (int i = 0; i < 8; i++) {
            const int row = srow + i * 16;
            float4 bv = valid ? *(const float4*)(asp_base + row * H2c + kd)
                              : make_float4(0.f,0.f,0.f,0.f);
            saspp[i] += bv.x * w2v.x + bv.y * w2v.y + bv.z * w2v.z + bv.w * w2v.w;
            ushort4 pv;
            pv.x = f2bf(bv.x);
            pv.y = f2bf(bv.y);
            pv.z = f2bf(bv.z);
            pv.w = f2bf(bv.w);
            *(ushort4*)(&Bs[row * LDK + d0]) = pv;
        }
        __syncthreads();

        // ---- MFMA: 2 k-steps of 32; wave computes 64x64 as 4x4 of 16x16 ----
#pragma unroll
        for (int ks = 0; ks < 2; ks++) {
            const int kk = ks * 32 + quad * 8;   // A/B frag: [m=lane&15][k=quad*8+j]
            bf16x8 afr[4], bfr[4];
#pragma unroll
            for (int t = 0; t < 4; t++) {
                const int ar = wm * 64 + t * 16 + l15;
                afr[t] = *(const bf16x8*)(&As[ar * LDK + kk]);
                const int br = wn * 64 + t * 16 + l15;
                bfr[t] = *(const bf16x8*)(&Bs[br * LDK + kk]);
            }
#pragma unroll
            for (int tm = 0; tm < 4; tm++)
#pragma unroll
                for (int tn = 0; tn < 4; tn++)
                    acc[tm][tn] = __builtin_amdgcn_mfma_f32_16x16x32_bf16(
                        afr[tm], bfr[tn], acc[tm][tn], 0, 0, 0);
        }
        __syncthreads();
    }

    // ---- reduce s_ctx / s_asp partials (reuse As as scratch: 128x16 f32 = 8 KB) ----
    float* red = (float*)As;
#pragma unroll
    for (int i = 0; i < 8; i++) red[(srow + i * 16) * 16 + scg] = sctxp[i];
    __syncthreads();
    if (tid < BM) {
        float s = 0.f;
#pragma unroll
        for (int c = 0; c < 16; c++) s += red[tid * 16 + c];
        sA[tid] = s;
    }
    __syncthreads();
#pragma unroll
    for (int i = 0; i < 8; i++) red[(srow + i * 16) * 16 + scg] = saspp[i];
    __syncthreads();
    if (tid < BN) {
        float s = 0.f;
#pragma unroll
        for (int c = 0; c < 16; c++) s += red[tid * 16 + c];
        sB[tid] = s;
    }
    __syncthreads();

    // ---- epilogue: D mapping n=lane&15, m=quad*4+reg; add s_ctx[m] + s_asp[n] ----
    float* out_base = out + ((size_t)b * L1c + rowBase) * L2c;
#pragma unroll
    for (int tm = 0; tm < 4; tm++) {
#pragma unroll
        for (int tn = 0; tn < 4; tn++) {
            const int col = wn * 64 + tn * 16 + l15;
            const float sbv = sB[col];
#pragma unroll
            for (int r = 0; r < 4; r++) {
                const int m = wm * 64 + tm * 16 + quad * 4 + r;
                out_base[(size_t)m * L2c + col] = acc[tm][tn][r] + sA[m] + sbv;
            }
        }
    }
}

extern "C" void kernel_launch(void* const* d_in, const int* in_sizes, int n_in,
                              void* d_out, int out_size, void* d_ws, size_t ws_size,
                              hipStream_t stream) {
    // inputs: [0]=batch_size (int scalar), [1]=ctx f32, [2]=asp f32, [3]=w_u f32
    const float* ctx = (const float*)d_in[1];
    const float* asp = (const float*)d_in[2];
    const float* w_u = (const float*)d_in[3];
    float* out = (float*)d_out;

    dim3 grid(L1c / BM, Bn);   // 8 x 128 = 1024 blocks
    align_kernel<<<grid, 256, 0, stream>>>(ctx, asp, w_u, out);
}

// Round 2
// 500.853 us; speedup vs baseline: 1.1351x; 1.1351x over previous
//
#include <hip/hip_runtime.h>
#include <hip/hip_bf16.h>

// Problem constants (AlignmentMatrix): B=128, L1=1024, L2=128, H2=600
static constexpr int Bn  = 128;
static constexpr int L1c = 1024;
static constexpr int L2c = 128;
static constexpr int H2c = 600;

#define BM 128
#define BN 128
#define BK 64
#define LDK 72              // BK + 8 pad shorts; row stride 144 B (16B-aligned, non-pow2 banks)
static constexpr int NCHUNK = (H2c + BK - 1) / BK;   // 10 (last chunk: 24 valid cols, zero-padded)

typedef __attribute__((ext_vector_type(8))) __bf16 bf16x8;
typedef __attribute__((ext_vector_type(4))) float  f32x4;

__device__ __forceinline__ unsigned short f2bf(float f) {
    // round-to-nearest-even f32 -> bf16
    unsigned int u = __float_as_uint(f);
    u += 0x7FFFu + ((u >> 16) & 1u);
    return (unsigned short)(u >> 16);
}

// 512 threads = 8 waves in a 4x2 grid of 32x64 sub-tiles.
// Pipeline: regs hold chunk k at loop top -> convert+ds_write -> barrier ->
// issue chunk k+1 loads (in flight during MFMA) -> MFMA -> barrier.
__global__ __launch_bounds__(512, 4)
void align_kernel(const float* __restrict__ ctx, const float* __restrict__ asp,
                  const float* __restrict__ w_u, float* __restrict__ out)
{
    __shared__ unsigned short As[BM * LDK];   // 18432 B, (ctx*w3) in bf16
    __shared__ unsigned short Bs[BN * LDK];   // 18432 B, asp in bf16
    __shared__ float sA[BM];                  // s_ctx for block rows
    __shared__ float sB[BN];                  // s_asp for block cols

    const int b       = blockIdx.y;
    const int rowBase = blockIdx.x * BM;
    const int tid  = threadIdx.x;
    const int lane = tid & 63;
    const int wave = tid >> 6;     // 0..7
    const int wm   = wave >> 1;    // 0..3: 32-row band
    const int wn   = wave & 1;     // 0..1: 64-col half
    const int quad = lane >> 4;
    const int l15  = lane & 15;

    const float* ctx_base = ctx + ((size_t)b * L1c + rowBase) * H2c;
    const float* asp_base = asp + (size_t)b * L2c * H2c;
    const float* w1 = w_u;
    const float* w2 = w_u + H2c;
    const float* w3 = w_u + 2 * H2c;

    // staging: thread (srow,scg) covers rows {srow+32i, i<4}, cols [scg*4, scg*4+3]
    const int srow = tid >> 4;     // 0..31
    const int scg  = tid & 15;     // 0..15
    const int d0   = scg * 4;      // 0..60

    f32x4 acc[2][4];
    const f32x4 zero4 = {0.f, 0.f, 0.f, 0.f};
#pragma unroll
    for (int i = 0; i < 2; i++)
#pragma unroll
        for (int j = 0; j < 4; j++) acc[i][j] = zero4;

    float sctxp[4], saspp[4];
#pragma unroll
    for (int i = 0; i < 4; i++) { sctxp[i] = 0.f; saspp[i] = 0.f; }

    float4 Apre[4], Bpre[4], w1v, w2v, w3v;

    // ---- prologue: load chunk 0 (always fully valid) ----
    {
        const int kd = d0;
        w1v = *(const float4*)(w1 + kd);
        w2v = *(const float4*)(w2 + kd);
        w3v = *(const float4*)(w3 + kd);
#pragma unroll
        for (int i = 0; i < 4; i++) {
            const int row = srow + i * 32;
            Apre[i] = *(const float4*)(ctx_base + row * H2c + kd);
            Bpre[i] = *(const float4*)(asp_base + row * H2c + kd);
        }
    }

    for (int kc = 0; kc < NCHUNK; kc++) {
        // ---- convert + write chunk kc from regs; fuse rank-1 partial dots ----
#pragma unroll
        for (int i = 0; i < 4; i++) {
            const int row = srow + i * 32;
            float4 av = Apre[i];
            sctxp[i] += av.x * w1v.x + av.y * w1v.y + av.z * w1v.z + av.w * w1v.w;
            ushort4 pv;
            pv.x = f2bf(av.x * w3v.x);
            pv.y = f2bf(av.y * w3v.y);
            pv.z = f2bf(av.z * w3v.z);
            pv.w = f2bf(av.w * w3v.w);
            *(ushort4*)(&As[row * LDK + d0]) = pv;

            float4 bv = Bpre[i];
            saspp[i] += bv.x * w2v.x + bv.y * w2v.y + bv.z * w2v.z + bv.w * w2v.w;
            ushort4 qv;
            qv.x = f2bf(bv.x);
            qv.y = f2bf(bv.y);
            qv.z = f2bf(bv.z);
            qv.w = f2bf(bv.w);
            *(ushort4*)(&Bs[row * LDK + d0]) = qv;
        }
        __syncthreads();   // staged tile visible to all waves

        // ---- issue chunk kc+1 loads NOW: in flight during the MFMA phase ----
        if (kc + 1 < NCHUNK) {
            const int kd = (kc + 1) * BK + d0;
            const bool valid = (kd < H2c);   // whole float4 valid or not (H2c%4==0)
            const float4 z4 = make_float4(0.f, 0.f, 0.f, 0.f);
            w1v = valid ? *(const float4*)(w1 + kd) : z4;
            w2v = valid ? *(const float4*)(w2 + kd) : z4;
            w3v = valid ? *(const float4*)(w3 + kd) : z4;
#pragma unroll
            for (int i = 0; i < 4; i++) {
                const int row = srow + i * 32;
                Apre[i] = valid ? *(const float4*)(ctx_base + row * H2c + kd) : z4;
                Bpre[i] = valid ? *(const float4*)(asp_base + row * H2c + kd) : z4;
            }
        }

        // ---- MFMA: 2 k-steps of 32; wave computes 32x64 as 2x4 of 16x16 ----
#pragma unroll
        for (int ks = 0; ks < 2; ks++) {
            const int kk = ks * 32 + quad * 8;   // A/B frag: [m=lane&15][k=quad*8+j]
            bf16x8 afr[2], bfr[4];
#pragma unroll
            for (int t = 0; t < 2; t++)
                afr[t] = *(const bf16x8*)(&As[(wm * 32 + t * 16 + l15) * LDK + kk]);
#pragma unroll
            for (int t = 0; t < 4; t++)
                bfr[t] = *(const bf16x8*)(&Bs[(wn * 64 + t * 16 + l15) * LDK + kk]);
#pragma unroll
            for (int tm = 0; tm < 2; tm++)
#pragma unroll
                for (int tn = 0; tn < 4; tn++)
                    acc[tm][tn] = __builtin_amdgcn_mfma_f32_16x16x32_bf16(
                        afr[tm], bfr[tn], acc[tm][tn], 0, 0, 0);
        }
        __syncthreads();
    }

    // ---- reduce s_ctx / s_asp partials (reuse As as scratch: 128x16 f32 = 8 KB) ----
    float* red = (float*)As;
#pragma unroll
    for (int i = 0; i < 4; i++) red[(srow + i * 32) * 16 + scg] = sctxp[i];
    __syncthreads();
    if (tid < BM) {
        float s = 0.f;
#pragma unroll
        for (int c = 0; c < 16; c++) s += red[tid * 16 + c];
        sA[tid] = s;
    }
    __syncthreads();
#pragma unroll
    for (int i = 0; i < 4; i++) red[(srow + i * 32) * 16 + scg] = saspp[i];
    __syncthreads();
    if (tid < BN) {
        float s = 0.f;
#pragma unroll
        for (int c = 0; c < 16; c++) s += red[tid * 16 + c];
        sB[tid] = s;
    }
    __syncthreads();

    // ---- epilogue: D mapping col=lane&15, row=quad*4+reg; add s_ctx[m] + s_asp[n] ----
    float* out_base = out + ((size_t)b * L1c + rowBase) * L2c;
#pragma unroll
    for (int tm = 0; tm < 2; tm++) {
#pragma unroll
        for (int tn = 0; tn < 4; tn++) {
            const int col = wn * 64 + tn * 16 + l15;
            const float sbv = sB[col];
#pragma unroll
            for (int r = 0; r < 4; r++) {
                const int m = wm * 32 + tm * 16 + quad * 4 + r;
                out_base[(size_t)m * L2c + col] = acc[tm][tn][r] + sA[m] + sbv;
            }
        }
    }
}

extern "C" void kernel_launch(void* const* d_in, const int* in_sizes, int n_in,
                              void* d_out, int out_size, void* d_ws, size_t ws_size,
                              hipStream_t stream) {
    // inputs: [0]=batch_size (int scalar), [1]=ctx f32, [2]=asp f32, [3]=w_u f32
    const float* ctx = (const float*)d_in[1];
    const float* asp = (const float*)d_in[2];
    const float* w_u = (const float*)d_in[3];
    float* out = (float*)d_out;

    dim3 grid(L1c / BM, Bn);   // 8 x 128 = 1024 blocks, 512 threads each
    align_kernel<<<grid, 512, 0, stream>>>(ctx, asp, w_u, out);
}